// Round 17
// baseline (431.838 us; speedup 1.0000x reference)
//
#include <hip/hip_runtime.h>
#include <hip/hip_bf16.h>
#include <hip/hip_cooperative_groups.h>
#include <stdint.h>

namespace cg = cooperative_groups;

typedef __bf16 bf16x8 __attribute__((ext_vector_type(8)));
typedef float f32x4 __attribute__((ext_vector_type(4)));
typedef float f32x2 __attribute__((ext_vector_type(2)));
typedef unsigned short u16;
typedef u16 ushort2v __attribute__((ext_vector_type(2)));
typedef u16 ushort4v __attribute__((ext_vector_type(4)));
typedef u16 ushort8v __attribute__((ext_vector_type(8)));

__device__ __forceinline__ u16 f2bf(float f) {
    union { float f; uint32_t u; } v; v.f = f;
    uint32_t u = v.u + 0x7FFFu + ((v.u >> 16) & 1u);
    return (u16)(u >> 16);
}
__device__ __forceinline__ float bf2f(u16 b) {
    union { uint32_t u; float f; } v; v.u = ((uint32_t)b) << 16;
    return v.f;
}
__device__ __forceinline__ float silu_f(float v) {
    return v / (1.0f + __expf(-v));
}
__device__ __forceinline__ void gload_lds16(const u16* g, u16* l) {
    __builtin_amdgcn_global_load_lds(
        (const __attribute__((address_space(1))) void*)g,
        (__attribute__((address_space(3))) void*)l, 16, 0, 0);
}

// ---------------- fused prep kernel (block-range dispatch) ----------------
__device__ __forceinline__ void trans_tile(
        const float* __restrict__ src, u16* __restrict__ dst, int R, int C,
        int bc, int br, float (*tt)[33], int tid) {
    const int tx = tid & 31, ty = tid >> 5;
#pragma unroll
    for (int i = 0; i < 4; i++)
        tt[ty + i * 8][tx] = src[(int64_t)(br * 32 + ty + i * 8) * C + bc * 32 + tx];
    __syncthreads();
    const int wx = tid & 15, wy = tid >> 4;
#pragma unroll
    for (int i = 0; i < 2; i++) {
        int c = wy + i * 16;
        ushort2v o = { f2bf(tt[wx * 2][c]), f2bf(tt[wx * 2 + 1][c]) };
        *(ushort2v*)&dst[(int64_t)(bc * 32 + c) * R + br * 32 + wx * 2] = o;
    }
}

__global__ __launch_bounds__(256) void prep_k(
        const float* __restrict__ x, u16* __restrict__ x_bf,
        const float* __restrict__ Wi, u16* __restrict__ Wti,
        const float* __restrict__ Wo, u16* __restrict__ Wto,
        const float* __restrict__ wx, u16* __restrict__ wxt) {
    __shared__ float tt[32][33];
    const int blk = blockIdx.x, tid = threadIdx.x;
    if (blk < 4096) {
        int64_t i = ((int64_t)blk * 256 + tid) * 8;
        float4 v0 = *(const float4*)&x[i];
        float4 v1 = *(const float4*)&x[i + 4];
        ushort8v o = { f2bf(v0.x), f2bf(v0.y), f2bf(v0.z), f2bf(v0.w),
                       f2bf(v1.x), f2bf(v1.y), f2bf(v1.z), f2bf(v1.w) };
        *(ushort8v*)&x_bf[i] = o;
    } else if (blk < 8192) {
        int t = blk - 4096;        // W_in 1024x4096 -> Wt_in 4096x1024
        trans_tile(Wi, Wti, 1024, 4096, t & 127, t >> 7, tt, tid);
    } else if (blk < 10240) {
        int t = blk - 8192;        // W_out 2048x1024 -> Wt_out 1024x2048
        trans_tile(Wo, Wto, 2048, 1024, t & 31, t >> 5, tt, tid);
    } else {
        int idx = (blk - 10240) * 256 + tid;
        int j = idx >> 11, d = idx & 2047;
        wxt[idx] = (j < 33) ? f2bf(wx[d * 33 + j]) : (u16)0;
    }
}

// =======================================================================
// GEMM1: deep-pipelined MFMA GEMM (round-8/10 best). FROZEN.
// =======================================================================
template<int M_REP, int WARPS_M, int B_HALVES, bool OUT_BF16>
__global__ __launch_bounds__(512) void gemm_dp(
        const u16* __restrict__ A, const u16* __restrict__ Bt,
        void* __restrict__ Cout, int nbn_sh, int NT, int lda, int ldb, int ldc) {
    constexpr int WARPS_N = 8 / WARPS_M;
    constexpr int QPT = M_REP / 2;
    constexpr int WV_M = M_REP * 16;
    constexpr int BN = WARPS_N * 64;
    constexpr int B_T = BN * 64;

    __shared__ __align__(16) u16 As[2 * 16384];
    __shared__ __align__(16) u16 Bs[2 * B_T];

    const int tid = threadIdx.x;
    const int wave = tid >> 6;
    const int lane = tid & 63;
    const int wm = wave / WARPS_N, wn = wave % WARPS_N;
    const int fr = lane & 15, fq = lane >> 4;

    const int nwg = gridDim.x;
    const int cpx = nwg >> 3;
    const int swz = (blockIdx.x & 7) * cpx + (blockIdx.x >> 3);
    const int bm = swz >> nbn_sh;
    const int bn = swz & ((1 << nbn_sh) - 1);

    const int srow = tid >> 3;
    const int scol8 = ((tid & 7) ^ (srow & 7)) * 8;
    const u16* gA = A + (int64_t)(bm * 256 + srow) * lda + scol8;
    const u16* gB = Bt + (int64_t)(bn * BN + srow) * ldb + scol8;
    const int64_t lda64 = lda, ldb64 = ldb;

    const int ksw0 = ((fq) ^ (fr & 7)) * 8;
    const int ksw1 = ((4 + fq) ^ (fr & 7)) * 8;
    const int arow0 = (wm * WV_M + fr) * 64;
    const int brow0 = (wn * 64 + fr) * 64;

    auto STAGE_A_HALF = [&](int kt, int buf, int h) {
#pragma unroll
        for (int j = 0; j < 2; ++j)
            gload_lds16(gA + (int64_t)(h * 128 + j * 64) * lda64 + kt * 64,
                        &As[buf * 16384 + h * 8192 + j * 4096 + tid * 8]);
    };
    auto STAGE_B_HALF = [&](int kt, int buf, int h) {
#pragma unroll
        for (int j = 0; j < 2; ++j)
            gload_lds16(gB + (int64_t)(h * 128 + j * 64) * ldb64 + kt * 64,
                        &Bs[buf * B_T + h * 8192 + j * 4096 + tid * 8]);
    };

    f32x4 acc[M_REP][4] = {};

    STAGE_A_HALF(0, 0, 0); STAGE_A_HALF(0, 0, 1);
#pragma unroll
    for (int h = 0; h < B_HALVES; ++h) STAGE_B_HALF(0, 0, h);
#pragma unroll
    for (int h = 0; h < B_HALVES; ++h) STAGE_B_HALF(1, 1, h);
    if constexpr (B_HALVES == 2) { asm volatile("s_waitcnt vmcnt(4)" ::: "memory"); }
    else                         { asm volatile("s_waitcnt vmcnt(2)" ::: "memory"); }
    __builtin_amdgcn_s_barrier();

    const int NI = NT >> 1;
    for (int s = 0; s < NI; ++s) {
        const bool more = (s + 1 < NI);
#pragma unroll
        for (int t = 0; t < 2; ++t) {
            const u16* Ab = &As[t * 16384];
            const u16* Bb = &Bs[t * B_T];
            bf16x8 breg[4][2];
            bf16x8 areg[2][2][2];
#pragma unroll
            for (int q = 0; q < QPT; ++q) {
                const int p = q & 1;
                if (q == 0) {
#pragma unroll
                    for (int n = 0; n < 4; ++n) {
                        breg[n][0] = *(const bf16x8*)(Bb + brow0 + n * 1024 + ksw0);
                        breg[n][1] = *(const bf16x8*)(Bb + brow0 + n * 1024 + ksw1);
                    }
#pragma unroll
                    for (int j = 0; j < 2; ++j) {
                        areg[0][j][0] = *(const bf16x8*)(Ab + arow0 + j * 1024 + ksw0);
                        areg[0][j][1] = *(const bf16x8*)(Ab + arow0 + j * 1024 + ksw1);
                    }
                }
                __builtin_amdgcn_s_setprio(1);
                if (q + 1 < QPT) {
#pragma unroll
                    for (int j = 0; j < 2; ++j) {
                        areg[p ^ 1][j][0] = *(const bf16x8*)(Ab + arow0 + (2 * (q + 1) + j) * 1024 + ksw0);
                        areg[p ^ 1][j][1] = *(const bf16x8*)(Ab + arow0 + (2 * (q + 1) + j) * 1024 + ksw1);
                    }
                }
#pragma unroll
                for (int j = 0; j < 2; ++j)
#pragma unroll
                    for (int n = 0; n < 4; ++n) {
                        acc[2 * q + j][n] = __builtin_amdgcn_mfma_f32_16x16x32_bf16(
                            areg[p][j][0], breg[n][0], acc[2 * q + j][n], 0, 0, 0);
                        acc[2 * q + j][n] = __builtin_amdgcn_mfma_f32_16x16x32_bf16(
                            areg[p][j][1], breg[n][1], acc[2 * q + j][n], 0, 0, 0);
                    }
                if (q + 1 < QPT) {
#pragma unroll
                    for (int g = 0; g < 4; ++g) {
                        __builtin_amdgcn_sched_group_barrier(0x008, 2, 0);
                        __builtin_amdgcn_sched_group_barrier(0x100, 1, 0);
                        __builtin_amdgcn_sched_group_barrier(0x008, 2, 0);
                    }
                }
                __builtin_amdgcn_s_setprio(0);
                if constexpr (QPT == 4) {
                    if (t == 0 && q == 0)         STAGE_A_HALF(2 * s + 1, 1, 0);
                    if (t == 0 && q == 1)         STAGE_A_HALF(2 * s + 1, 1, 1);
                    if (t == 0 && q == 2 && more) STAGE_B_HALF(2 * s + 2, 0, 0);
                    if (t == 0 && q == 3 && more) STAGE_B_HALF(2 * s + 2, 0, 1);
                    if (t == 1 && q == 0 && more) STAGE_A_HALF(2 * s + 2, 0, 0);
                    if (t == 1 && q == 1 && more) STAGE_A_HALF(2 * s + 2, 0, 1);
                    if (t == 1 && q == 2 && more) STAGE_B_HALF(2 * s + 3, 1, 0);
                    if (t == 1 && q == 3 && more) STAGE_B_HALF(2 * s + 3, 1, 1);
                } else {
                    if (t == 0 && q == 0)         STAGE_A_HALF(2 * s + 1, 1, 0);
                    if (t == 0 && q == 1) {       STAGE_A_HALF(2 * s + 1, 1, 1);
                        if (more)                 STAGE_B_HALF(2 * s + 2, 0, 0); }
                    if (t == 1 && q == 0 && more) STAGE_A_HALF(2 * s + 2, 0, 0);
                    if (t == 1 && q == 1 && more) { STAGE_A_HALF(2 * s + 2, 0, 1);
                                                    STAGE_B_HALF(2 * s + 3, 1, 0); }
                }
                if (q == QPT - 1) {
                    if (more) {
                        if constexpr (B_HALVES == 2) { asm volatile("s_waitcnt vmcnt(4)" ::: "memory"); }
                        else                         { asm volatile("s_waitcnt vmcnt(2)" ::: "memory"); }
                    } else {
                        asm volatile("s_waitcnt vmcnt(0)" ::: "memory");
                    }
                }
                __builtin_amdgcn_s_barrier();
            }
        }
    }

#pragma unroll
    for (int m = 0; m < M_REP; ++m) {
#pragma unroll
        for (int n = 0; n < 4; ++n) {
            const int col = bn * BN + wn * 64 + n * 16 + fr;
#pragma unroll
            for (int r = 0; r < 4; ++r) {
                const int row = bm * 256 + wm * WV_M + m * 16 + fq * 4 + r;
                if constexpr (OUT_BF16)
                    ((u16*)Cout)[(int64_t)row * ldc + col] = f2bf(acc[m][n][r]);
                else
                    ((float*)Cout)[(int64_t)row * ldc + col] = acc[m][n][r];
            }
        }
    }
}

// =======================================================================
// GEMM3: 128x128 tile, 256 threads, 2 blocks/CU (round-11). FROZEN.
// =======================================================================
__global__ __launch_bounds__(256) void gemm3_k(
        const u16* __restrict__ A, const u16* __restrict__ Bt,
        float* __restrict__ Cout, int NT, int lda, int ldb, int ldc) {
    __shared__ __align__(16) u16 As[2 * 8192];
    __shared__ __align__(16) u16 Bs[2 * 8192];

    const int tid = threadIdx.x;
    const int wave = tid >> 6;
    const int lane = tid & 63;
    const int wm = wave >> 1, wn = wave & 1;
    const int fr = lane & 15, fq = lane >> 4;

    const int nwg = gridDim.x;
    const int cpx = nwg >> 3;
    const int swz = (blockIdx.x & 7) * cpx + (blockIdx.x >> 3);
    const int bm = swz >> 3;
    const int bn = swz & 7;

    const int srow = tid >> 3;
    const int scol8 = ((tid & 7) ^ (srow & 7)) * 8;
    const u16* gA = A + (int64_t)(bm * 128 + srow) * lda + scol8;
    const u16* gB = Bt + (int64_t)(bn * 128 + srow) * ldb + scol8;
    const int64_t lda64 = lda, ldb64 = ldb;

    const int ksw0 = ((fq) ^ (fr & 7)) * 8;
    const int ksw1 = ((4 + fq) ^ (fr & 7)) * 8;
    const int arow0 = (wm * 64 + fr) * 64;
    const int brow0 = (wn * 64 + fr) * 64;

    auto STAGE_A = [&](int kt, int buf, int h) {
#pragma unroll
        for (int j = 0; j < 2; ++j)
            gload_lds16(gA + (int64_t)(h * 64 + j * 32) * lda64 + kt * 64,
                        &As[buf * 8192 + h * 4096 + j * 2048 + tid * 8]);
    };
    auto STAGE_B = [&](int kt, int buf, int h) {
#pragma unroll
        for (int j = 0; j < 2; ++j)
            gload_lds16(gB + (int64_t)(h * 64 + j * 32) * ldb64 + kt * 64,
                        &Bs[buf * 8192 + h * 4096 + j * 2048 + tid * 8]);
    };

    f32x4 acc[4][4] = {};

    STAGE_A(0, 0, 0); STAGE_A(0, 0, 1);
    STAGE_B(0, 0, 0); STAGE_B(0, 0, 1);
    STAGE_B(1, 1, 0); STAGE_B(1, 1, 1);
    asm volatile("s_waitcnt vmcnt(4)" ::: "memory");
    __builtin_amdgcn_s_barrier();

    for (int t = 0; t < NT; ++t) {
        const u16* Ab = &As[(t & 1) * 8192];
        const u16* Bb = &Bs[(t & 1) * 8192];
        bf16x8 breg[4][2];
        bf16x8 areg[2][2][2];
#pragma unroll
        for (int n = 0; n < 4; ++n) {
            breg[n][0] = *(const bf16x8*)(Bb + brow0 + n * 1024 + ksw0);
            breg[n][1] = *(const bf16x8*)(Bb + brow0 + n * 1024 + ksw1);
        }
#pragma unroll
        for (int j = 0; j < 2; ++j) {
            areg[0][j][0] = *(const bf16x8*)(Ab + arow0 + j * 1024 + ksw0);
            areg[0][j][1] = *(const bf16x8*)(Ab + arow0 + j * 1024 + ksw1);
        }
        if (t + 1 < NT) STAGE_A(t + 1, (t + 1) & 1, 0);
        __builtin_amdgcn_s_barrier();
        asm volatile("s_waitcnt lgkmcnt(0)" ::: "memory");
        __builtin_amdgcn_sched_barrier(0);
        __builtin_amdgcn_s_setprio(1);
#pragma unroll
        for (int j = 0; j < 2; ++j) {
            areg[1][j][0] = *(const bf16x8*)(Ab + arow0 + (2 + j) * 1024 + ksw0);
            areg[1][j][1] = *(const bf16x8*)(Ab + arow0 + (2 + j) * 1024 + ksw1);
        }
#pragma unroll
        for (int j = 0; j < 2; ++j)
#pragma unroll
            for (int n = 0; n < 4; ++n) {
                acc[j][n] = __builtin_amdgcn_mfma_f32_16x16x32_bf16(
                    areg[0][j][0], breg[n][0], acc[j][n], 0, 0, 0);
                acc[j][n] = __builtin_amdgcn_mfma_f32_16x16x32_bf16(
                    areg[0][j][1], breg[n][1], acc[j][n], 0, 0, 0);
            }
#pragma unroll
        for (int g = 0; g < 4; ++g) {
            __builtin_amdgcn_sched_group_barrier(0x008, 2, 0);
            __builtin_amdgcn_sched_group_barrier(0x100, 1, 0);
            __builtin_amdgcn_sched_group_barrier(0x008, 2, 0);
        }
        __builtin_amdgcn_s_setprio(0);
        __builtin_amdgcn_s_barrier();
        if (t + 1 < NT) STAGE_A(t + 1, (t + 1) & 1, 1);
        if (t + 2 < NT) { STAGE_B(t + 2, t & 1, 0); STAGE_B(t + 2, t & 1, 1); }
        __builtin_amdgcn_s_barrier();
        asm volatile("s_waitcnt lgkmcnt(0)" ::: "memory");
        __builtin_amdgcn_sched_barrier(0);
        __builtin_amdgcn_s_setprio(1);
#pragma unroll
        for (int j = 0; j < 2; ++j)
#pragma unroll
            for (int n = 0; n < 4; ++n) {
                acc[2 + j][n] = __builtin_amdgcn_mfma_f32_16x16x32_bf16(
                    areg[1][j][0], breg[n][0], acc[2 + j][n], 0, 0, 0);
                acc[2 + j][n] = __builtin_amdgcn_mfma_f32_16x16x32_bf16(
                    areg[1][j][1], breg[n][1], acc[2 + j][n], 0, 0, 0);
            }
        __builtin_amdgcn_s_setprio(0);
        if (t + 2 < NT) { asm volatile("s_waitcnt vmcnt(4)" ::: "memory"); }
        else            { asm volatile("s_waitcnt vmcnt(0)" ::: "memory"); }
        __builtin_amdgcn_s_barrier();
    }

#pragma unroll
    for (int m = 0; m < 4; ++m) {
#pragma unroll
        for (int n = 0; n < 4; ++n) {
            const int col = bn * 128 + wn * 64 + n * 16 + fr;
#pragma unroll
            for (int r = 0; r < 4; ++r) {
                const int row = bm * 128 + wm * 64 + m * 16 + fq * 4 + r;
                Cout[(int64_t)row * ldc + col] = acc[m][n][r];
            }
        }
    }
}

// =======================================================================
// Fused conv(4)+bias+SiLU + ssm projection + softplus finalize. FROZEN.
// =======================================================================
__global__ __launch_bounds__(256) void conv_ssm_k(
        const u16* __restrict__ xz, const float* __restrict__ cw,
        const float* __restrict__ cb, const u16* __restrict__ wxt,
        u16* __restrict__ xc, float* __restrict__ dB, float* __restrict__ Cm) {
    __shared__ __align__(16) u16 Xs[16][2064];
    __shared__ float Sred[4][16][48];
    __shared__ float deltas[16];
    const int blk = blockIdx.x;
    const int b = blk >> 7, lb = blk & 127;
    const int l0 = lb << 4;
    const int64_t r0 = (int64_t)b * 2048 + l0;
    const int tid = threadIdx.x;
    const int d0 = tid * 8;

    float w[8][4], bias[8];
#pragma unroll
    for (int j = 0; j < 8; j++) {
        float4 wv = *(const float4*)&cw[(d0 + j) * 4];
        w[j][0] = wv.x; w[j][1] = wv.y; w[j][2] = wv.z; w[j][3] = wv.w;
        bias[j] = cb[d0 + j];
    }
    float win[4][8];
#pragma unroll
    for (int r = 0; r < 3; r++) {
        int l = l0 - 3 + r;
        if (l < 0) {
#pragma unroll
            for (int j = 0; j < 8; j++) win[r][j] = 0.f;
        } else {
            ushort8v v = *(const ushort8v*)&xz[((int64_t)b * 2048 + l) * 4096 + d0];
#pragma unroll
            for (int j = 0; j < 8; j++) win[r][j] = bf2f(v[j]);
        }
    }
    ushort8v rows[16];
#pragma unroll
    for (int li = 0; li < 16; li++)
        rows[li] = *(const ushort8v*)&xz[(r0 + li) * 4096 + d0];

#pragma unroll
    for (int li = 0; li < 16; li++) {
#pragma unroll
        for (int j = 0; j < 8; j++) win[(3 + li) & 3][j] = bf2f(rows[li][j]);
        ushort8v o;
#pragma unroll
        for (int j = 0; j < 8; j++) {
            float s = bias[j];
#pragma unroll
            for (int k = 0; k < 4; k++) s += w[j][k] * win[(li + k) & 3][j];
            o[j] = f2bf(silu_f(s));
        }
        *(ushort8v*)&xc[(r0 + li) * 2048 + d0] = o;
        *(ushort8v*)&Xs[li][d0] = o;
    }
    __syncthreads();

    const int kc = tid >> 6;
    const int lane = tid & 63;
    const int fr = lane & 15, fq = lane >> 4;
    const u16* bp = wxt + (int64_t)fr * 2048 + kc * 512 + fq * 8;
    const u16* ap = &Xs[fr][kc * 512 + fq * 8];
    f32x4 acc0 = {}, acc1 = {}, acc2 = {};
#pragma unroll 4
    for (int k = 0; k < 512; k += 32) {
        bf16x8 av = *(const bf16x8*)(ap + k);
        bf16x8 b0 = *(const bf16x8*)(bp + k);
        bf16x8 b1 = *(const bf16x8*)(bp + 16 * 2048 + k);
        bf16x8 b2 = *(const bf16x8*)(bp + 32 * 2048 + k);
        acc0 = __builtin_amdgcn_mfma_f32_16x16x32_bf16(av, b0, acc0, 0, 0, 0);
        acc1 = __builtin_amdgcn_mfma_f32_16x16x32_bf16(av, b1, acc1, 0, 0, 0);
        acc2 = __builtin_amdgcn_mfma_f32_16x16x32_bf16(av, b2, acc2, 0, 0, 0);
    }
#pragma unroll
    for (int r = 0; r < 4; r++) {
        Sred[kc][fq * 4 + r][fr]      = acc0[r];
        Sred[kc][fq * 4 + r][16 + fr] = acc1[r];
        Sred[kc][fq * 4 + r][32 + fr] = acc2[r];
    }
    __syncthreads();
    if (tid < 16) {
        float s0 = Sred[0][tid][0] + Sred[1][tid][0] + Sred[2][tid][0] + Sred[3][tid][0];
        deltas[tid] = (s0 > 20.f) ? s0 : log1pf(__expf(s0));
    }
    __syncthreads();
    {
        const int row = tid >> 4, n = tid & 15;
        float sB = Sred[0][row][1 + n] + Sred[1][row][1 + n] +
                   Sred[2][row][1 + n] + Sred[3][row][1 + n];
        float sC = Sred[0][row][17 + n] + Sred[1][row][17 + n] +
                   Sred[2][row][17 + n] + Sred[3][row][17 + n];
        dB[(r0 + row) * 16 + n] = deltas[row] * sB * (1.0f / 2048.0f);
        Cm[(r0 + row) * 16 + n] = sC;
    }
}

// ---------------- standalone tail kernels (fallback path) ----------------
__global__ __launch_bounds__(256) void h_part_k(
        const u16* __restrict__ xc, const float* __restrict__ dB,
        float* __restrict__ hp) {
    const int blk = blockIdx.x;
    const int dt = blk & 3, b = (blk >> 2) & 3, lc = blk >> 4;
    const int d = dt * 512 + threadIdx.x * 2;
    const u16* xp = xc + ((int64_t)(b * 2048 + lc * 64)) * 2048 + d;
    const f32x2* dbp = (const f32x2*)(dB + (int64_t)(b * 2048 + lc * 64) * 16);
    f32x2 acc0[8] = {}, acc1[8] = {};
    for (int l = 0; l < 64; l++) {
        ushort2v xv = *(const ushort2v*)&xp[(int64_t)l * 2048];
        float x0 = bf2f(xv[0]), x1 = bf2f(xv[1]);
#pragma unroll
        for (int q = 0; q < 8; q++) {
            f32x2 dv = dbp[l * 8 + q];
            acc0[q] += dv * x0;
            acc1[q] += dv * x1;
        }
    }
    float* o = hp + ((int64_t)((lc * 4 + b) * 2048 + d)) * 16;
#pragma unroll
    for (int q = 0; q < 8; q++) *(f32x2*)&o[q * 2] = acc0[q];
#pragma unroll
    for (int q = 0; q < 8; q++) *(f32x2*)&o[16 + q * 2] = acc1[q];
}

__global__ void h_red_k(const float* __restrict__ hp, float* __restrict__ h) {
    const int i4 = blockIdx.x * 256 + threadIdx.x;  // < 32768
    f32x4 s = {};
#pragma unroll
    for (int c = 0; c < 32; c++)
        s += *(const f32x4*)&hp[(int64_t)c * 131072 + i4 * 4];
    *(f32x4*)&h[i4 * 4] = s;
}

__global__ __launch_bounds__(256) void y_gate_k(
        u16* __restrict__ xz, const u16* __restrict__ xc,
        const float* __restrict__ h, const float* __restrict__ Cm,
        const float* __restrict__ Dp) {
    const int blk = blockIdx.x;
    const int lc = blk & 127, b = blk >> 7;
    const int d0 = threadIdx.x * 8;
    const float* hpp = h + ((int64_t)(b * 2048 + d0)) * 16;
    float hreg[8][16];
#pragma unroll
    for (int i = 0; i < 8; i++)
#pragma unroll
        for (int n4 = 0; n4 < 4; n4++) {
            f32x4 hv = *(const f32x4*)&hpp[i * 16 + n4 * 4];
            hreg[i][n4 * 4 + 0] = hv[0]; hreg[i][n4 * 4 + 1] = hv[1];
            hreg[i][n4 * 4 + 2] = hv[2]; hreg[i][n4 * 4 + 3] = hv[3];
        }
    float Dv[8];
    {
        f32x4 dv0 = *(const f32x4*)&Dp[d0];
        f32x4 dv1 = *(const f32x4*)&Dp[d0 + 4];
#pragma unroll
        for (int i = 0; i < 4; i++) { Dv[i] = dv0[i]; Dv[4 + i] = dv1[i]; }
    }
    __shared__ float Cs[16][16];
    if (threadIdx.x < 64)
        ((float4*)&Cs[0][0])[threadIdx.x] =
            ((const float4*)(Cm + (int64_t)(b * 2048 + lc * 16) * 16))[threadIdx.x];
    __syncthreads();
#pragma unroll 4
    for (int li = 0; li < 16; li++) {
        const int64_t rowz = (int64_t)(b * 2048 + lc * 16 + li);
        ushort8v xcv = *(const ushort8v*)&xc[rowz * 2048 + d0];
        ushort8v zv = *(const ushort8v*)&xz[rowz * 4096 + 2048 + d0];
        ushort8v o;
#pragma unroll
        for (int i = 0; i < 8; i++) {
            float s = Dv[i] * bf2f(xcv[i]);
#pragma unroll
            for (int n = 0; n < 16; n++) s += hreg[i][n] * Cs[li][n];
            o[i] = f2bf(s * silu_f(bf2f(zv[i])));
        }
        *(ushort8v*)&xz[rowz * 4096 + d0] = o;
    }
}

// =======================================================================
// Fused tail (cooperative): h_part -> h_red -> y_gate.  512 blocks x 256
// threads, LDS = 1KB (Cs only) -> co-residency trivially >= 2 blocks/CU.
// Phase code + bid geometry byte-identical to the standalone kernels ->
// bit-identical output.  threadfence + grid.sync between phases.
// =======================================================================
__global__ __launch_bounds__(256, 2) void fused_tail_k(
        u16* __restrict__ xz, const u16* __restrict__ xc,
        const float* __restrict__ dB, const float* __restrict__ Cm,
        float* __restrict__ hp, float* __restrict__ h,
        const float* __restrict__ Dp) {
    cg::grid_group grid = cg::this_grid();
    __shared__ float Cs[16][16];
    const int tid = threadIdx.x;
    const int bid = blockIdx.x;

    // ===== phase 1: h partial (identical to h_part_k) =====
    {
        const int dt = bid & 3, b = (bid >> 2) & 3, lc = bid >> 4;
        const int d = dt * 512 + tid * 2;
        const u16* xp = xc + ((int64_t)(b * 2048 + lc * 64)) * 2048 + d;
        const f32x2* dbp = (const f32x2*)(dB + (int64_t)(b * 2048 + lc * 64) * 16);
        f32x2 acc0[8] = {}, acc1[8] = {};
        for (int l = 0; l < 64; l++) {
            ushort2v xv = *(const ushort2v*)&xp[(int64_t)l * 2048];
            float x0 = bf2f(xv[0]), x1 = bf2f(xv[1]);
#pragma unroll
            for (int q = 0; q < 8; q++) {
                f32x2 dv = dbp[l * 8 + q];
                acc0[q] += dv * x0;
                acc1[q] += dv * x1;
            }
        }
        float* o = hp + ((int64_t)((lc * 4 + b) * 2048 + d)) * 16;
#pragma unroll
        for (int q = 0; q < 8; q++) *(f32x2*)&o[q * 2] = acc0[q];
#pragma unroll
        for (int q = 0; q < 8; q++) *(f32x2*)&o[16 + q * 2] = acc1[q];
    }
    __threadfence();
    grid.sync();

    // ===== phase 2: h reduction (blocks 0..127, identical to h_red_k) =====
    if (bid < 128) {
        const int i4 = bid * 256 + tid;  // < 32768
        f32x4 s = {};
#pragma unroll
        for (int c = 0; c < 32; c++)
            s += *(const f32x4*)&hp[(int64_t)c * 131072 + i4 * 4];
        *(f32x4*)&h[i4 * 4] = s;
    }
    __threadfence();
    grid.sync();

    // ===== phase 3: y gate (identical to y_gate_k) =====
    {
        const int lc = bid & 127, b = bid >> 7;
        const int d0 = tid * 8;
        const float* hpp = h + ((int64_t)(b * 2048 + d0)) * 16;
        float hreg[8][16];
#pragma unroll
        for (int i = 0; i < 8; i++)
#pragma unroll
            for (int n4 = 0; n4 < 4; n4++) {
                f32x4 hv = *(const f32x4*)&hpp[i * 16 + n4 * 4];
                hreg[i][n4 * 4 + 0] = hv[0]; hreg[i][n4 * 4 + 1] = hv[1];
                hreg[i][n4 * 4 + 2] = hv[2]; hreg[i][n4 * 4 + 3] = hv[3];
            }
        float Dv[8];
        {
            f32x4 dv0 = *(const f32x4*)&Dp[d0];
            f32x4 dv1 = *(const f32x4*)&Dp[d0 + 4];
#pragma unroll
            for (int i = 0; i < 4; i++) { Dv[i] = dv0[i]; Dv[4 + i] = dv1[i]; }
        }
        if (tid < 64)
            ((float4*)&Cs[0][0])[tid] =
                ((const float4*)(Cm + (int64_t)(b * 2048 + lc * 16) * 16))[tid];
        __syncthreads();
#pragma unroll 4
        for (int li = 0; li < 16; li++) {
            const int64_t rowz = (int64_t)(b * 2048 + lc * 16 + li);
            ushort8v xcv = *(const ushort8v*)&xc[rowz * 2048 + d0];
            ushort8v zv = *(const ushort8v*)&xz[rowz * 4096 + 2048 + d0];
            ushort8v o;
#pragma unroll
            for (int i = 0; i < 8; i++) {
                float s = Dv[i] * bf2f(xcv[i]);
#pragma unroll
                for (int n = 0; n < 16; n++) s += hreg[i][n] * Cs[li][n];
                o[i] = f2bf(s * silu_f(bf2f(zv[i])));
            }
            *(ushort8v*)&xz[rowz * 4096 + d0] = o;
        }
    }
}

extern "C" void kernel_launch(void* const* d_in, const int* in_sizes, int n_in,
                              void* d_out, int out_size, void* d_ws, size_t ws_size,
                              hipStream_t stream) {
    (void)in_sizes; (void)n_in; (void)out_size; (void)ws_size;
    const float* x      = (const float*)d_in[0];
    const float* W_in   = (const float*)d_in[1];
    const float* conv_w = (const float*)d_in[2];
    const float* conv_b = (const float*)d_in[3];
    const float* W_xp   = (const float*)d_in[4];
    const float* Dp     = (const float*)d_in[6];   // d_in[5] = A_log, unused by reference
    const float* W_out  = (const float*)d_in[7];
    float* out = (float*)d_out;
    char* ws = (char*)d_ws;

    // x_bf/Wt_in are dead after GEMM1; dB/Cm/h/hp alias that region.
    u16*   x_bf   = (u16*)(ws);                   // [0, 16 MB)
    float* dB     = (float*)(ws);                 // 524,288
    float* Cm     = (float*)(ws + 524288);        // 524,288
    float* h      = (float*)(ws + 1048576);       // 524,288
    float* hp     = (float*)(ws + 1572864);       // 16 MB -> ends 18,350,080 (over dead Wt_in)
    u16*   Wt_in  = (u16*)(ws + 16777216);        // 8 MB (dead after GEMM1)
    u16*   Wt_out = (u16*)(ws + 25165824);        // 4 MB
    u16*   Wxt    = (u16*)(ws + 29360128);        // 196,608
    u16*   xz     = (u16*)(ws + 29556736);        // 64 MB
    u16*   xcv    = (u16*)(ws + 96665600);        // 32 MB

    prep_k<<<10624, 256, 0, stream>>>(x, x_bf, W_in, Wt_in, W_out, Wt_out, W_xp, Wxt);
    // xz = x @ W_in : M=8192 N=4096 K=1024
    gemm_dp<8, 2, 2, true><<<512, 512, 0, stream>>>(x_bf, Wt_in, xz, 4, 16, 1024, 1024, 4096);
    conv_ssm_k<<<512, 256, 0, stream>>>(xz, conv_w, conv_b, Wxt, xcv, dB, Cm);
    // fused tail (cooperative, 1KB LDS). On launch rejection fall back to
    // the standalone kernels (identical math -> identical output).
    {
        void* args[] = { &xz, &xcv, &dB, &Cm, &hp, &h, &Dp };
        hipError_t ce = hipLaunchCooperativeKernel((void*)fused_tail_k,
                                                   dim3(512), dim3(256),
                                                   args, 0, stream);
        if (ce != hipSuccess) {
            h_part_k<<<512, 256, 0, stream>>>(xcv, dB, hp);
            h_red_k<<<128, 256, 0, stream>>>(hp, h);
            y_gate_k<<<512, 256, 0, stream>>>(xz, xcv, h, Cm, Dp);
        }
    }
    // out = y @ W_out : M=8192 N=1024 K=2048; grid 64x8=512, 2 blocks/CU
    gemm3_k<<<512, 256, 0, stream>>>(xz, Wt_out, out, 32, 4096, 2048, 1024);
}

// Round 18
// 204.569 us; speedup vs baseline: 2.1110x; 2.1110x over previous
//
#include <hip/hip_runtime.h>
#include <hip/hip_bf16.h>
#include <stdint.h>

typedef __bf16 bf16x8 __attribute__((ext_vector_type(8)));
typedef float f32x4 __attribute__((ext_vector_type(4)));
typedef float f32x2 __attribute__((ext_vector_type(2)));
typedef unsigned short u16;
typedef u16 ushort2v __attribute__((ext_vector_type(2)));
typedef u16 ushort4v __attribute__((ext_vector_type(4)));
typedef u16 ushort8v __attribute__((ext_vector_type(8)));

__device__ __forceinline__ u16 f2bf(float f) {
    union { float f; uint32_t u; } v; v.f = f;
    uint32_t u = v.u + 0x7FFFu + ((v.u >> 16) & 1u);
    return (u16)(u >> 16);
}
__device__ __forceinline__ float bf2f(u16 b) {
    union { uint32_t u; float f; } v; v.u = ((uint32_t)b) << 16;
    return v.f;
}
__device__ __forceinline__ float silu_f(float v) {
    return v / (1.0f + __expf(-v));
}
__device__ __forceinline__ void gload_lds16(const u16* g, u16* l) {
    __builtin_amdgcn_global_load_lds(
        (const __attribute__((address_space(1))) void*)g,
        (__attribute__((address_space(3))) void*)l, 16, 0, 0);
}

// ---------------- fused prep kernel (block-range dispatch) ----------------
__device__ __forceinline__ void trans_tile(
        const float* __restrict__ src, u16* __restrict__ dst, int R, int C,
        int bc, int br, float (*tt)[33], int tid) {
    const int tx = tid & 31, ty = tid >> 5;
#pragma unroll
    for (int i = 0; i < 4; i++)
        tt[ty + i * 8][tx] = src[(int64_t)(br * 32 + ty + i * 8) * C + bc * 32 + tx];
    __syncthreads();
    const int wx = tid & 15, wy = tid >> 4;
#pragma unroll
    for (int i = 0; i < 2; i++) {
        int c = wy + i * 16;
        ushort2v o = { f2bf(tt[wx * 2][c]), f2bf(tt[wx * 2 + 1][c]) };
        *(ushort2v*)&dst[(int64_t)(bc * 32 + c) * R + br * 32 + wx * 2] = o;
    }
}

__global__ __launch_bounds__(256) void prep_k(
        const float* __restrict__ x, u16* __restrict__ x_bf,
        const float* __restrict__ Wi, u16* __restrict__ Wti,
        const float* __restrict__ Wo, u16* __restrict__ Wto,
        const float* __restrict__ wx, u16* __restrict__ wxt) {
    __shared__ float tt[32][33];
    const int blk = blockIdx.x, tid = threadIdx.x;
    if (blk < 4096) {
        // x -> bf16: 8 floats/thread, one 16B store
        int64_t i = ((int64_t)blk * 256 + tid) * 8;
        float4 v0 = *(const float4*)&x[i];
        float4 v1 = *(const float4*)&x[i + 4];
        ushort8v o = { f2bf(v0.x), f2bf(v0.y), f2bf(v0.z), f2bf(v0.w),
                       f2bf(v1.x), f2bf(v1.y), f2bf(v1.z), f2bf(v1.w) };
        *(ushort8v*)&x_bf[i] = o;
    } else if (blk < 8192) {
        int t = blk - 4096;        // W_in 1024x4096 -> Wt_in 4096x1024
        trans_tile(Wi, Wti, 1024, 4096, t & 127, t >> 7, tt, tid);
    } else if (blk < 10240) {
        int t = blk - 8192;        // W_out 2048x1024 -> Wt_out 1024x2048
        trans_tile(Wo, Wto, 2048, 1024, t & 31, t >> 5, tt, tid);
    } else {
        int idx = (blk - 10240) * 256 + tid;
        int j = idx >> 11, d = idx & 2047;
        wxt[idx] = (j < 33) ? f2bf(wx[d * 33 + j]) : (u16)0;
    }
}

// =======================================================================
// GEMM1: deep-pipelined MFMA GEMM (round-8/10 best). FROZEN.
// 16x16x32 is the right MFMA shape for this staging scheme: 128B LDS rows
// make bank = slot-index only; 16x16 reads alias 2-way (free, m136),
// 32x32 reads alias 4-way (round-14: +6.3M conflicts, +7us). Scheduling
// closed by rounds 2,3,4,5,6,9 bracketing ~74us/37% from both sides.
// =======================================================================
template<int M_REP, int WARPS_M, int B_HALVES, bool OUT_BF16>
__global__ __launch_bounds__(512) void gemm_dp(
        const u16* __restrict__ A, const u16* __restrict__ Bt,
        void* __restrict__ Cout, int nbn_sh, int NT, int lda, int ldb, int ldc) {
    constexpr int WARPS_N = 8 / WARPS_M;
    constexpr int QPT = M_REP / 2;
    constexpr int WV_M = M_REP * 16;
    constexpr int BN = WARPS_N * 64;
    constexpr int B_T = BN * 64;

    __shared__ __align__(16) u16 As[2 * 16384];
    __shared__ __align__(16) u16 Bs[2 * B_T];

    const int tid = threadIdx.x;
    const int wave = tid >> 6;
    const int lane = tid & 63;
    const int wm = wave / WARPS_N, wn = wave % WARPS_N;
    const int fr = lane & 15, fq = lane >> 4;

    const int nwg = gridDim.x;
    const int cpx = nwg >> 3;
    const int swz = (blockIdx.x & 7) * cpx + (blockIdx.x >> 3);
    const int bm = swz >> nbn_sh;
    const int bn = swz & ((1 << nbn_sh) - 1);

    const int srow = tid >> 3;
    const int scol8 = ((tid & 7) ^ (srow & 7)) * 8;
    const u16* gA = A + (int64_t)(bm * 256 + srow) * lda + scol8;
    const u16* gB = Bt + (int64_t)(bn * BN + srow) * ldb + scol8;
    const int64_t lda64 = lda, ldb64 = ldb;

    const int ksw0 = ((fq) ^ (fr & 7)) * 8;
    const int ksw1 = ((4 + fq) ^ (fr & 7)) * 8;
    const int arow0 = (wm * WV_M + fr) * 64;
    const int brow0 = (wn * 64 + fr) * 64;

    auto STAGE_A_HALF = [&](int kt, int buf, int h) {
#pragma unroll
        for (int j = 0; j < 2; ++j)
            gload_lds16(gA + (int64_t)(h * 128 + j * 64) * lda64 + kt * 64,
                        &As[buf * 16384 + h * 8192 + j * 4096 + tid * 8]);
    };
    auto STAGE_B_HALF = [&](int kt, int buf, int h) {
#pragma unroll
        for (int j = 0; j < 2; ++j)
            gload_lds16(gB + (int64_t)(h * 128 + j * 64) * ldb64 + kt * 64,
                        &Bs[buf * B_T + h * 8192 + j * 4096 + tid * 8]);
    };

    f32x4 acc[M_REP][4] = {};

    STAGE_A_HALF(0, 0, 0); STAGE_A_HALF(0, 0, 1);
#pragma unroll
    for (int h = 0; h < B_HALVES; ++h) STAGE_B_HALF(0, 0, h);
#pragma unroll
    for (int h = 0; h < B_HALVES; ++h) STAGE_B_HALF(1, 1, h);
    if constexpr (B_HALVES == 2) { asm volatile("s_waitcnt vmcnt(4)" ::: "memory"); }
    else                         { asm volatile("s_waitcnt vmcnt(2)" ::: "memory"); }
    __builtin_amdgcn_s_barrier();

    const int NI = NT >> 1;
    for (int s = 0; s < NI; ++s) {
        const bool more = (s + 1 < NI);
#pragma unroll
        for (int t = 0; t < 2; ++t) {
            const u16* Ab = &As[t * 16384];
            const u16* Bb = &Bs[t * B_T];
            bf16x8 breg[4][2];
            bf16x8 areg[2][2][2];
#pragma unroll
            for (int q = 0; q < QPT; ++q) {
                const int p = q & 1;
                if (q == 0) {
#pragma unroll
                    for (int n = 0; n < 4; ++n) {
                        breg[n][0] = *(const bf16x8*)(Bb + brow0 + n * 1024 + ksw0);
                        breg[n][1] = *(const bf16x8*)(Bb + brow0 + n * 1024 + ksw1);
                    }
#pragma unroll
                    for (int j = 0; j < 2; ++j) {
                        areg[0][j][0] = *(const bf16x8*)(Ab + arow0 + j * 1024 + ksw0);
                        areg[0][j][1] = *(const bf16x8*)(Ab + arow0 + j * 1024 + ksw1);
                    }
                }
                __builtin_amdgcn_s_setprio(1);
                if (q + 1 < QPT) {
#pragma unroll
                    for (int j = 0; j < 2; ++j) {
                        areg[p ^ 1][j][0] = *(const bf16x8*)(Ab + arow0 + (2 * (q + 1) + j) * 1024 + ksw0);
                        areg[p ^ 1][j][1] = *(const bf16x8*)(Ab + arow0 + (2 * (q + 1) + j) * 1024 + ksw1);
                    }
                }
#pragma unroll
                for (int j = 0; j < 2; ++j)
#pragma unroll
                    for (int n = 0; n < 4; ++n) {
                        acc[2 * q + j][n] = __builtin_amdgcn_mfma_f32_16x16x32_bf16(
                            areg[p][j][0], breg[n][0], acc[2 * q + j][n], 0, 0, 0);
                        acc[2 * q + j][n] = __builtin_amdgcn_mfma_f32_16x16x32_bf16(
                            areg[p][j][1], breg[n][1], acc[2 * q + j][n], 0, 0, 0);
                    }
                if (q + 1 < QPT) {
#pragma unroll
                    for (int g = 0; g < 4; ++g) {
                        __builtin_amdgcn_sched_group_barrier(0x008, 2, 0);
                        __builtin_amdgcn_sched_group_barrier(0x100, 1, 0);
                        __builtin_amdgcn_sched_group_barrier(0x008, 2, 0);
                    }
                }
                __builtin_amdgcn_s_setprio(0);
                if constexpr (QPT == 4) {
                    if (t == 0 && q == 0)         STAGE_A_HALF(2 * s + 1, 1, 0);
                    if (t == 0 && q == 1)         STAGE_A_HALF(2 * s + 1, 1, 1);
                    if (t == 0 && q == 2 && more) STAGE_B_HALF(2 * s + 2, 0, 0);
                    if (t == 0 && q == 3 && more) STAGE_B_HALF(2 * s + 2, 0, 1);
                    if (t == 1 && q == 0 && more) STAGE_A_HALF(2 * s + 2, 0, 0);
                    if (t == 1 && q == 1 && more) STAGE_A_HALF(2 * s + 2, 0, 1);
                    if (t == 1 && q == 2 && more) STAGE_B_HALF(2 * s + 3, 1, 0);
                    if (t == 1 && q == 3 && more) STAGE_B_HALF(2 * s + 3, 1, 1);
                } else {
                    if (t == 0 && q == 0)         STAGE_A_HALF(2 * s + 1, 1, 0);
                    if (t == 0 && q == 1) {       STAGE_A_HALF(2 * s + 1, 1, 1);
                        if (more)                 STAGE_B_HALF(2 * s + 2, 0, 0); }
                    if (t == 1 && q == 0 && more) STAGE_A_HALF(2 * s + 2, 0, 0);
                    if (t == 1 && q == 1 && more) { STAGE_A_HALF(2 * s + 2, 0, 1);
                                                    STAGE_B_HALF(2 * s + 3, 1, 0); }
                }
                if (q == QPT - 1) {
                    if (more) {
                        if constexpr (B_HALVES == 2) { asm volatile("s_waitcnt vmcnt(4)" ::: "memory"); }
                        else                         { asm volatile("s_waitcnt vmcnt(2)" ::: "memory"); }
                    } else {
                        asm volatile("s_waitcnt vmcnt(0)" ::: "memory");
                    }
                }
                __builtin_amdgcn_s_barrier();
            }
        }
    }

#pragma unroll
    for (int m = 0; m < M_REP; ++m) {
#pragma unroll
        for (int n = 0; n < 4; ++n) {
            const int col = bn * BN + wn * 64 + n * 16 + fr;
#pragma unroll
            for (int r = 0; r < 4; ++r) {
                const int row = bm * 256 + wm * WV_M + m * 16 + fq * 4 + r;
                if constexpr (OUT_BF16)
                    ((u16*)Cout)[(int64_t)row * ldc + col] = f2bf(acc[m][n][r]);
                else
                    ((float*)Cout)[(int64_t)row * ldc + col] = acc[m][n][r];
            }
        }
    }
}

// =======================================================================
// GEMM3: 128x128 tile, 256 threads, 2 blocks/CU (round-11). FROZEN.
// =======================================================================
__global__ __launch_bounds__(256) void gemm3_k(
        const u16* __restrict__ A, const u16* __restrict__ Bt,
        float* __restrict__ Cout, int NT, int lda, int ldb, int ldc) {
    __shared__ __align__(16) u16 As[2 * 8192];
    __shared__ __align__(16) u16 Bs[2 * 8192];

    const int tid = threadIdx.x;
    const int wave = tid >> 6;
    const int lane = tid & 63;
    const int wm = wave >> 1, wn = wave & 1;
    const int fr = lane & 15, fq = lane >> 4;

    const int nwg = gridDim.x;
    const int cpx = nwg >> 3;
    const int swz = (blockIdx.x & 7) * cpx + (blockIdx.x >> 3);
    const int bm = swz >> 3;
    const int bn = swz & 7;

    const int srow = tid >> 3;
    const int scol8 = ((tid & 7) ^ (srow & 7)) * 8;
    const u16* gA = A + (int64_t)(bm * 128 + srow) * lda + scol8;
    const u16* gB = Bt + (int64_t)(bn * 128 + srow) * ldb + scol8;
    const int64_t lda64 = lda, ldb64 = ldb;

    const int ksw0 = ((fq) ^ (fr & 7)) * 8;
    const int ksw1 = ((4 + fq) ^ (fr & 7)) * 8;
    const int arow0 = (wm * 64 + fr) * 64;
    const int brow0 = (wn * 64 + fr) * 64;

    auto STAGE_A = [&](int kt, int buf, int h) {
#pragma unroll
        for (int j = 0; j < 2; ++j)
            gload_lds16(gA + (int64_t)(h * 64 + j * 32) * lda64 + kt * 64,
                        &As[buf * 8192 + h * 4096 + j * 2048 + tid * 8]);
    };
    auto STAGE_B = [&](int kt, int buf, int h) {
#pragma unroll
        for (int j = 0; j < 2; ++j)
            gload_lds16(gB + (int64_t)(h * 64 + j * 32) * ldb64 + kt * 64,
                        &Bs[buf * 8192 + h * 4096 + j * 2048 + tid * 8]);
    };

    f32x4 acc[4][4] = {};

    STAGE_A(0, 0, 0); STAGE_A(0, 0, 1);
    STAGE_B(0, 0, 0); STAGE_B(0, 0, 1);
    STAGE_B(1, 1, 0); STAGE_B(1, 1, 1);
    asm volatile("s_waitcnt vmcnt(4)" ::: "memory");
    __builtin_amdgcn_s_barrier();

    for (int t = 0; t < NT; ++t) {
        const u16* Ab = &As[(t & 1) * 8192];
        const u16* Bb = &Bs[(t & 1) * 8192];
        bf16x8 breg[4][2];
        bf16x8 areg[2][2][2];
#pragma unroll
        for (int n = 0; n < 4; ++n) {
            breg[n][0] = *(const bf16x8*)(Bb + brow0 + n * 1024 + ksw0);
            breg[n][1] = *(const bf16x8*)(Bb + brow0 + n * 1024 + ksw1);
        }
#pragma unroll
        for (int j = 0; j < 2; ++j) {
            areg[0][j][0] = *(const bf16x8*)(Ab + arow0 + j * 1024 + ksw0);
            areg[0][j][1] = *(const bf16x8*)(Ab + arow0 + j * 1024 + ksw1);
        }
        if (t + 1 < NT) STAGE_A(t + 1, (t + 1) & 1, 0);
        __builtin_amdgcn_s_barrier();
        asm volatile("s_waitcnt lgkmcnt(0)" ::: "memory");
        __builtin_amdgcn_sched_barrier(0);
        __builtin_amdgcn_s_setprio(1);
#pragma unroll
        for (int j = 0; j < 2; ++j) {
            areg[1][j][0] = *(const bf16x8*)(Ab + arow0 + (2 + j) * 1024 + ksw0);
            areg[1][j][1] = *(const bf16x8*)(Ab + arow0 + (2 + j) * 1024 + ksw1);
        }
#pragma unroll
        for (int j = 0; j < 2; ++j)
#pragma unroll
            for (int n = 0; n < 4; ++n) {
                acc[j][n] = __builtin_amdgcn_mfma_f32_16x16x32_bf16(
                    areg[0][j][0], breg[n][0], acc[j][n], 0, 0, 0);
                acc[j][n] = __builtin_amdgcn_mfma_f32_16x16x32_bf16(
                    areg[0][j][1], breg[n][1], acc[j][n], 0, 0, 0);
            }
#pragma unroll
        for (int g = 0; g < 4; ++g) {
            __builtin_amdgcn_sched_group_barrier(0x008, 2, 0);
            __builtin_amdgcn_sched_group_barrier(0x100, 1, 0);
            __builtin_amdgcn_sched_group_barrier(0x008, 2, 0);
        }
        __builtin_amdgcn_s_setprio(0);
        __builtin_amdgcn_s_barrier();
        if (t + 1 < NT) STAGE_A(t + 1, (t + 1) & 1, 1);
        if (t + 2 < NT) { STAGE_B(t + 2, t & 1, 0); STAGE_B(t + 2, t & 1, 1); }
        __builtin_amdgcn_s_barrier();
        asm volatile("s_waitcnt lgkmcnt(0)" ::: "memory");
        __builtin_amdgcn_sched_barrier(0);
        __builtin_amdgcn_s_setprio(1);
#pragma unroll
        for (int j = 0; j < 2; ++j)
#pragma unroll
            for (int n = 0; n < 4; ++n) {
                acc[2 + j][n] = __builtin_amdgcn_mfma_f32_16x16x32_bf16(
                    areg[1][j][0], breg[n][0], acc[2 + j][n], 0, 0, 0);
                acc[2 + j][n] = __builtin_amdgcn_mfma_f32_16x16x32_bf16(
                    areg[1][j][1], breg[n][1], acc[2 + j][n], 0, 0, 0);
            }
        __builtin_amdgcn_s_setprio(0);
        if (t + 2 < NT) { asm volatile("s_waitcnt vmcnt(4)" ::: "memory"); }
        else            { asm volatile("s_waitcnt vmcnt(0)" ::: "memory"); }
        __builtin_amdgcn_s_barrier();
    }

#pragma unroll
    for (int m = 0; m < 4; ++m) {
#pragma unroll
        for (int n = 0; n < 4; ++n) {
            const int col = bn * 128 + wn * 64 + n * 16 + fr;
#pragma unroll
            for (int r = 0; r < 4; ++r) {
                const int row = bm * 128 + wm * 64 + m * 16 + fq * 4 + r;
                Cout[(int64_t)row * ldc + col] = acc[m][n][r];
            }
        }
    }
}

// =======================================================================
// Fused conv(4)+bias+SiLU + ssm projection + softplus finalize. FROZEN.
// =======================================================================
__global__ __launch_bounds__(256) void conv_ssm_k(
        const u16* __restrict__ xz, const float* __restrict__ cw,
        const float* __restrict__ cb, const u16* __restrict__ wxt,
        u16* __restrict__ xc, float* __restrict__ dB, float* __restrict__ Cm) {
    __shared__ __align__(16) u16 Xs[16][2064];
    __shared__ float Sred[4][16][48];
    __shared__ float deltas[16];
    const int blk = blockIdx.x;
    const int b = blk >> 7, lb = blk & 127;
    const int l0 = lb << 4;
    const int64_t r0 = (int64_t)b * 2048 + l0;
    const int tid = threadIdx.x;
    const int d0 = tid * 8;

    float w[8][4], bias[8];
#pragma unroll
    for (int j = 0; j < 8; j++) {
        float4 wv = *(const float4*)&cw[(d0 + j) * 4];
        w[j][0] = wv.x; w[j][1] = wv.y; w[j][2] = wv.z; w[j][3] = wv.w;
        bias[j] = cb[d0 + j];
    }
    float win[4][8];
#pragma unroll
    for (int r = 0; r < 3; r++) {
        int l = l0 - 3 + r;
        if (l < 0) {
#pragma unroll
            for (int j = 0; j < 8; j++) win[r][j] = 0.f;
        } else {
            ushort8v v = *(const ushort8v*)&xz[((int64_t)b * 2048 + l) * 4096 + d0];
#pragma unroll
            for (int j = 0; j < 8; j++) win[r][j] = bf2f(v[j]);
        }
    }
    ushort8v rows[16];
#pragma unroll
    for (int li = 0; li < 16; li++)
        rows[li] = *(const ushort8v*)&xz[(r0 + li) * 4096 + d0];

#pragma unroll
    for (int li = 0; li < 16; li++) {
#pragma unroll
        for (int j = 0; j < 8; j++) win[(3 + li) & 3][j] = bf2f(rows[li][j]);
        ushort8v o;
#pragma unroll
        for (int j = 0; j < 8; j++) {
            float s = bias[j];
#pragma unroll
            for (int k = 0; k < 4; k++) s += w[j][k] * win[(li + k) & 3][j];
            o[j] = f2bf(silu_f(s));
        }
        *(ushort8v*)&xc[(r0 + li) * 2048 + d0] = o;
        *(ushort8v*)&Xs[li][d0] = o;
    }
    __syncthreads();

    const int kc = tid >> 6;
    const int lane = tid & 63;
    const int fr = lane & 15, fq = lane >> 4;
    const u16* bp = wxt + (int64_t)fr * 2048 + kc * 512 + fq * 8;
    const u16* ap = &Xs[fr][kc * 512 + fq * 8];
    f32x4 acc0 = {}, acc1 = {}, acc2 = {};
#pragma unroll 4
    for (int k = 0; k < 512; k += 32) {
        bf16x8 av = *(const bf16x8*)(ap + k);
        bf16x8 b0 = *(const bf16x8*)(bp + k);
        bf16x8 b1 = *(const bf16x8*)(bp + 16 * 2048 + k);
        bf16x8 b2 = *(const bf16x8*)(bp + 32 * 2048 + k);
        acc0 = __builtin_amdgcn_mfma_f32_16x16x32_bf16(av, b0, acc0, 0, 0, 0);
        acc1 = __builtin_amdgcn_mfma_f32_16x16x32_bf16(av, b1, acc1, 0, 0, 0);
        acc2 = __builtin_amdgcn_mfma_f32_16x16x32_bf16(av, b2, acc2, 0, 0, 0);
    }
#pragma unroll
    for (int r = 0; r < 4; r++) {
        Sred[kc][fq * 4 + r][fr]      = acc0[r];
        Sred[kc][fq * 4 + r][16 + fr] = acc1[r];
        Sred[kc][fq * 4 + r][32 + fr] = acc2[r];
    }
    __syncthreads();
    if (tid < 16) {
        float s0 = Sred[0][tid][0] + Sred[1][tid][0] + Sred[2][tid][0] + Sred[3][tid][0];
        deltas[tid] = (s0 > 20.f) ? s0 : log1pf(__expf(s0));
    }
    __syncthreads();
    {
        const int row = tid >> 4, n = tid & 15;
        float sB = Sred[0][row][1 + n] + Sred[1][row][1 + n] +
                   Sred[2][row][1 + n] + Sred[3][row][1 + n];
        float sC = Sred[0][row][17 + n] + Sred[1][row][17 + n] +
                   Sred[2][row][17 + n] + Sred[3][row][17 + n];
        dB[(r0 + row) * 16 + n] = deltas[row] * sB * (1.0f / 2048.0f);
        Cm[(r0 + row) * 16 + n] = sC;
    }
}

// h partial over 64-l chunks; thread owns 2 d-channels (ushort2 4B loads).
__global__ __launch_bounds__(256) void h_part_k(
        const u16* __restrict__ xc, const float* __restrict__ dB,
        float* __restrict__ hp) {
    const int blk = blockIdx.x;
    const int dt = blk & 3, b = (blk >> 2) & 3, lc = blk >> 4;
    const int d = dt * 512 + threadIdx.x * 2;
    const u16* xp = xc + ((int64_t)(b * 2048 + lc * 64)) * 2048 + d;
    const f32x2* dbp = (const f32x2*)(dB + (int64_t)(b * 2048 + lc * 64) * 16);
    f32x2 acc0[8] = {}, acc1[8] = {};
    for (int l = 0; l < 64; l++) {
        ushort2v xv = *(const ushort2v*)&xp[(int64_t)l * 2048];
        float x0 = bf2f(xv[0]), x1 = bf2f(xv[1]);
#pragma unroll
        for (int q = 0; q < 8; q++) {
            f32x2 dv = dbp[l * 8 + q];
            acc0[q] += dv * x0;
            acc1[q] += dv * x1;
        }
    }
    float* o = hp + ((int64_t)((lc * 4 + b) * 2048 + d)) * 16;
#pragma unroll
    for (int q = 0; q < 8; q++) *(f32x2*)&o[q * 2] = acc0[q];
#pragma unroll
    for (int q = 0; q < 8; q++) *(f32x2*)&o[16 + q * 2] = acc1[q];
}

// h reduction: f32x4 per thread, 128 blocks
__global__ void h_red_k(const float* __restrict__ hp, float* __restrict__ h) {
    const int i4 = blockIdx.x * 256 + threadIdx.x;  // < 32768
    f32x4 s = {};
#pragma unroll
    for (int c = 0; c < 32; c++)
        s += *(const f32x4*)&hp[(int64_t)c * 131072 + i4 * 4];
    *(f32x4*)&h[i4 * 4] = s;
}

// y gate: thread owns 8 d-channels; h/D preloads vectorized as f32x4.
__global__ __launch_bounds__(256) void y_gate_k(
        u16* __restrict__ xz, const u16* __restrict__ xc,
        const float* __restrict__ h, const float* __restrict__ Cm,
        const float* __restrict__ Dp) {
    const int blk = blockIdx.x;
    const int lc = blk & 127, b = blk >> 7;
    const int d0 = threadIdx.x * 8;
    const float* hpp = h + ((int64_t)(b * 2048 + d0)) * 16;
    float hreg[8][16];
#pragma unroll
    for (int i = 0; i < 8; i++)
#pragma unroll
        for (int n4 = 0; n4 < 4; n4++) {
            f32x4 hv = *(const f32x4*)&hpp[i * 16 + n4 * 4];
            hreg[i][n4 * 4 + 0] = hv[0]; hreg[i][n4 * 4 + 1] = hv[1];
            hreg[i][n4 * 4 + 2] = hv[2]; hreg[i][n4 * 4 + 3] = hv[3];
        }
    float Dv[8];
    {
        f32x4 dv0 = *(const f32x4*)&Dp[d0];
        f32x4 dv1 = *(const f32x4*)&Dp[d0 + 4];
#pragma unroll
        for (int i = 0; i < 4; i++) { Dv[i] = dv0[i]; Dv[4 + i] = dv1[i]; }
    }
    __shared__ float Cs[16][16];
    if (threadIdx.x < 64)
        ((float4*)&Cs[0][0])[threadIdx.x] =
            ((const float4*)(Cm + (int64_t)(b * 2048 + lc * 16) * 16))[threadIdx.x];
    __syncthreads();
#pragma unroll 4
    for (int li = 0; li < 16; li++) {
        const int64_t rowz = (int64_t)(b * 2048 + lc * 16 + li);
        ushort8v xcv = *(const ushort8v*)&xc[rowz * 2048 + d0];
        ushort8v zv = *(const ushort8v*)&xz[rowz * 4096 + 2048 + d0];
        ushort8v o;
#pragma unroll
        for (int i = 0; i < 8; i++) {
            float s = Dv[i] * bf2f(xcv[i]);
#pragma unroll
            for (int n = 0; n < 16; n++) s += hreg[i][n] * Cs[li][n];
            o[i] = f2bf(s * silu_f(bf2f(zv[i])));
        }
        *(ushort8v*)&xz[rowz * 4096 + d0] = o;
    }
}

extern "C" void kernel_launch(void* const* d_in, const int* in_sizes, int n_in,
                              void* d_out, int out_size, void* d_ws, size_t ws_size,
                              hipStream_t stream) {
    (void)in_sizes; (void)n_in; (void)out_size; (void)ws_size;
    const float* x      = (const float*)d_in[0];
    const float* W_in   = (const float*)d_in[1];
    const float* conv_w = (const float*)d_in[2];
    const float* conv_b = (const float*)d_in[3];
    const float* W_xp   = (const float*)d_in[4];
    const float* Dp     = (const float*)d_in[6];   // d_in[5] = A_log, unused by reference
    const float* W_out  = (const float*)d_in[7];
    float* out = (float*)d_out;
    char* ws = (char*)d_ws;

    // x_bf/Wt_in are dead after GEMM1; dB/Cm/h/hp alias that region.
    u16*   x_bf   = (u16*)(ws);                   // [0, 16 MB)
    float* dB     = (float*)(ws);                 // 524,288
    float* Cm     = (float*)(ws + 524288);        // 524,288
    float* h      = (float*)(ws + 1048576);       // 524,288
    float* hp     = (float*)(ws + 1572864);       // 16 MB -> ends 18,350,080 (over dead Wt_in)
    u16*   Wt_in  = (u16*)(ws + 16777216);        // 8 MB (dead after GEMM1)
    u16*   Wt_out = (u16*)(ws + 25165824);        // 4 MB
    u16*   Wxt    = (u16*)(ws + 29360128);        // 196,608
    u16*   xz     = (u16*)(ws + 29556736);        // 64 MB
    u16*   xcv    = (u16*)(ws + 96665600);        // 32 MB

    prep_k<<<10624, 256, 0, stream>>>(x, x_bf, W_in, Wt_in, W_out, Wt_out, W_xp, Wxt);
    // xz = x @ W_in : M=8192 N=4096 K=1024
    gemm_dp<8, 2, 2, true><<<512, 512, 0, stream>>>(x_bf, Wt_in, xz, 4, 16, 1024, 1024, 4096);
    conv_ssm_k<<<512, 256, 0, stream>>>(xz, conv_w, conv_b, Wxt, xcv, dB, Cm);
    h_part_k<<<512, 256, 0, stream>>>(xcv, dB, hp);
    h_red_k<<<128, 256, 0, stream>>>(hp, h);
    y_gate_k<<<512, 256, 0, stream>>>(xz, xcv, h, Cm, Dp);
    // out = y @ W_out : M=8192 N=1024 K=2048; grid 64x8=512, 2 blocks/CU
    gemm3_k<<<512, 256, 0, stream>>>(xz, Wt_out, out, 32, 4096, 2048, 1024);
}